// Round 4
// baseline (214.204 us; speedup 1.0000x reference)
//
#include <hip/hip_runtime.h>

// Tiny ViT forward, B=8192, fp32. Wave-per-image: lane t owns token t
// (lanes 50..63 clamp to token 49 — duplicate compute, never read).
// No LDS, no barriers. K/V broadcast lane->wave via v_readlane (uniform
// loop index -> SGPR operand). Weights read via wave-uniform global
// loads (s_load, scalar cache). One-pass softmax, no max subtraction
// (scores ~0.06 std; exp-safe by ~80 orders of magnitude).

#define T_TOK   50
#define WAVES_PB 4
#define THREADS (WAVES_PB * 64)
#define SCALE   0.35355339059327373f   // 8^-0.5

__device__ __forceinline__ float rl(float v, int s) {
    return __int_as_float(__builtin_amdgcn_readlane(__float_as_int(v), s));
}

__global__ __launch_bounds__(THREADS, 4) void vit_fwd(
    const float* __restrict__ images, const float* __restrict__ cls,
    const float* __restrict__ linW,
    const float* __restrict__ g1,  const float* __restrict__ be1,
    const float* __restrict__ Wq,  const float* __restrict__ Wk,
    const float* __restrict__ Wv,  const float* __restrict__ Pw,
    const float* __restrict__ Pb,  const float* __restrict__ g2,
    const float* __restrict__ be2, const float* __restrict__ W1,
    const float* __restrict__ bb1, const float* __restrict__ W2,
    const float* __restrict__ bb2, const float* __restrict__ mlpW,
    const float* __restrict__ mlpb,
    float* __restrict__ out, int B)
{
    const int lane = threadIdx.x & 63;
    const int wid  = threadIdx.x >> 6;
    const int gimg = blockIdx.x * WAVES_PB + wid;   // wave-uniform
    if (gimg >= B) return;
    const int t = (lane < T_TOK) ? lane : (T_TOK - 1);

    // ---- patch embed + positional ----
    float x[8];
    {
        const float FR[4] = {1.f, 0.1f, 0.01f, 0.001f};
        float pos[8];
        #pragma unroll
        for (int j = 0; j < 8; ++j) {
            float arg = (float)t * FR[j >> 1];
            pos[j] = (j & 1) ? __cosf(arg) : __sinf(arg);
        }
        if (t == 0) {
            #pragma unroll
            for (int e = 0; e < 8; ++e) x[e] = cls[e] + pos[e];
        } else {
            const int p = t - 1, pr = p / 7, pc = p - pr * 7;
            const float* ib = images + (size_t)gimg * 784 + pr * 112 + pc * 4;
            float pf[16];
            #pragma unroll
            for (int r = 0; r < 4; ++r) {
                float4 u = *reinterpret_cast<const float4*>(ib + r * 28);
                pf[r*4+0] = u.x; pf[r*4+1] = u.y;
                pf[r*4+2] = u.z; pf[r*4+3] = u.w;
            }
            #pragma unroll
            for (int e = 0; e < 8; ++e) {
                float a = 0.f;
                #pragma unroll
                for (int i = 0; i < 16; ++i) a += pf[i] * linW[e*16 + i];
                x[e] = a + pos[e];
            }
        }
    }

    for (int blk = 0; blk < 4; ++blk) {
        const int w8 = blk * 8, w64 = blk * 64, w256 = blk * 256, w32 = blk * 32;

        // ---- LN1 + q,k,v (k,v stay in this lane's registers) ----
        float q[8], kk[8], vv[8];
        {
            float mu = 0.f;
            #pragma unroll
            for (int d = 0; d < 8; ++d) mu += x[d];
            mu *= 0.125f;
            float var = 0.f;
            #pragma unroll
            for (int d = 0; d < 8; ++d) { float dd = x[d] - mu; var += dd * dd; }
            var *= 0.125f;
            const float rs = rsqrtf(var + 1e-5f);
            float h[8];
            #pragma unroll
            for (int d = 0; d < 8; ++d)
                h[d] = (x[d] - mu) * rs * g1[w8 + d] + be1[w8 + d];
            #pragma unroll
            for (int e = 0; e < 8; ++e) {
                float aq = 0.f, ak = 0.f, av = 0.f;
                #pragma unroll
                for (int d = 0; d < 8; ++d) {
                    aq += h[d] * Wq[w64 + e*8 + d];
                    ak += h[d] * Wk[w64 + e*8 + d];
                    av += h[d] * Wv[w64 + e*8 + d];
                }
                q[e] = aq * SCALE; kk[e] = ak; vv[e] = av;
            }
        }

        // ---- attention: broadcast k_s, v_s from lane s via readlane ----
        float l0 = 0.f, l1 = 0.f;
        float a00=0.f,a01=0.f,a02=0.f,a03=0.f;
        float a10=0.f,a11=0.f,a12=0.f,a13=0.f;
        #pragma unroll 2
        for (int s = 0; s < T_TOK; ++s) {
            float d0 = q[0]*rl(kk[0],s) + q[1]*rl(kk[1],s)
                     + q[2]*rl(kk[2],s) + q[3]*rl(kk[3],s);
            float d1 = q[4]*rl(kk[4],s) + q[5]*rl(kk[5],s)
                     + q[6]*rl(kk[6],s) + q[7]*rl(kk[7],s);
            float p0 = __expf(d0), p1 = __expf(d1);
            l0 += p0; l1 += p1;
            a00 += p0 * rl(vv[0],s); a01 += p0 * rl(vv[1],s);
            a02 += p0 * rl(vv[2],s); a03 += p0 * rl(vv[3],s);
            a10 += p1 * rl(vv[4],s); a11 += p1 * rl(vv[5],s);
            a12 += p1 * rl(vv[6],s); a13 += p1 * rl(vv[7],s);
        }
        float o[8];
        {
            const float r0 = 1.f / l0, r1 = 1.f / l1;
            o[0]=a00*r0; o[1]=a01*r0; o[2]=a02*r0; o[3]=a03*r0;
            o[4]=a10*r1; o[5]=a11*r1; o[6]=a12*r1; o[7]=a13*r1;
        }

        // ---- proj + residual + LN2 + FF ----
        float xn[8];
        #pragma unroll
        for (int e = 0; e < 8; ++e) {
            float a = Pb[w8 + e];
            #pragma unroll
            for (int d = 0; d < 8; ++d) a += o[d] * Pw[w64 + e*8 + d];
            xn[e] = x[e] + a;
        }
        {
            float mu = 0.f;
            #pragma unroll
            for (int d = 0; d < 8; ++d) mu += xn[d];
            mu *= 0.125f;
            float var = 0.f;
            #pragma unroll
            for (int d = 0; d < 8; ++d) { float dd = xn[d] - mu; var += dd * dd; }
            var *= 0.125f;
            const float rs2 = rsqrtf(var + 1e-5f);
            float h2[8];
            #pragma unroll
            for (int d = 0; d < 8; ++d)
                h2[d] = (xn[d] - mu) * rs2 * g2[w8 + d] + be2[w8 + d];
            float acc[8] = {0.f,0.f,0.f,0.f,0.f,0.f,0.f,0.f};
            #pragma unroll 4
            for (int f = 0; f < 32; ++f) {
                float a = bb1[w32 + f];
                #pragma unroll
                for (int d = 0; d < 8; ++d) a += h2[d] * W1[w256 + f*8 + d];
                a = fmaxf(a, 0.f);
                #pragma unroll
                for (int d = 0; d < 8; ++d) acc[d] += a * W2[w256 + d*32 + f];
            }
            #pragma unroll
            for (int d = 0; d < 8; ++d) x[d] = xn[d] + acc[d] + bb2[w8 + d];
        }
    }

    // ---- classification head: lane 0 (token 0) ----
    if (lane == 0) {
        float lg[10]; float mx = -1e30f;
        #pragma unroll
        for (int c = 0; c < 10; ++c) {
            float a = mlpb[c];
            #pragma unroll
            for (int d = 0; d < 8; ++d) a += x[d] * mlpW[c*8 + d];
            lg[c] = a; mx = fmaxf(mx, a);
        }
        float ssum = 0.f;
        #pragma unroll
        for (int c = 0; c < 10; ++c) { lg[c] = __expf(lg[c] - mx); ssum += lg[c]; }
        const float rsum = 1.f / ssum;
        #pragma unroll
        for (int c = 0; c < 10; ++c)
            out[(size_t)gimg*10 + c] = lg[c] * rsum;
    }
}

extern "C" void kernel_launch(void* const* d_in, const int* in_sizes, int n_in,
                              void* d_out, int out_size, void* d_ws, size_t ws_size,
                              hipStream_t stream) {
    const int B = in_sizes[0] / 784;
    const int nblk = (B + WAVES_PB - 1) / WAVES_PB;
    vit_fwd<<<nblk, THREADS, 0, stream>>>(
        (const float*)d_in[0],  (const float*)d_in[1],  (const float*)d_in[2],
        (const float*)d_in[3],  (const float*)d_in[4],  (const float*)d_in[5],
        (const float*)d_in[6],  (const float*)d_in[7],  (const float*)d_in[8],
        (const float*)d_in[9],  (const float*)d_in[10], (const float*)d_in[11],
        (const float*)d_in[12], (const float*)d_in[13], (const float*)d_in[14],
        (const float*)d_in[15], (const float*)d_in[16], (const float*)d_in[17],
        (float*)d_out, B);
}

// Round 5
// 104.741 us; speedup vs baseline: 2.0451x; 2.0451x over previous
//
#include <hip/hip_runtime.h>

// Tiny ViT forward, B=8192, fp32. Wave-per-image: lane t owns token t
// (lanes 50..63 clamp to 49; duplicate compute, benign duplicate LDS
// writes of identical data). K/V live in a PER-WAVE LDS region: no
// __syncthreads anywhere (single-wave producer/consumer, program order
// + compiler lgkmcnt waits suffice). Attention reads use wave-uniform
// address s -> hardware broadcast, conflict-free, on the LDS pipe.
// All dense math hand-vectorized as float2 -> v_pk_fma_f32 (packed
// fp32, 2 FMA/instr). Weights via wave-uniform global loads (s_load).
// One-pass softmax without max subtraction (scores ~0.06 std).

typedef float fx2 __attribute__((ext_vector_type(2)));

#define T_TOK    50
#define WAVES_PB 4
#define THREADS  (WAVES_PB * 64)
#define KVSTRIDE 20                  // floats per token (16 + 4 pad)
#define SCALE    0.35355339059327373f   // 8^-0.5

#if __has_builtin(__builtin_amdgcn_exp2f)
  #define FASTEXP(x) __builtin_amdgcn_exp2f(x)
  #define QSCALE (SCALE * 1.4426950408889634f)   // fold log2(e) into q
#else
  #define FASTEXP(x) __expf(x)
  #define QSCALE SCALE
#endif

__device__ __forceinline__ float hadd(fx2 v) { return v.x + v.y; }

__global__ __launch_bounds__(THREADS) void vit_fwd(
    const float* __restrict__ images, const float* __restrict__ cls,
    const float* __restrict__ linW,
    const float* __restrict__ g1,  const float* __restrict__ be1,
    const float* __restrict__ Wq,  const float* __restrict__ Wk,
    const float* __restrict__ Wv,  const float* __restrict__ Pw,
    const float* __restrict__ Pb,  const float* __restrict__ g2,
    const float* __restrict__ be2, const float* __restrict__ W1,
    const float* __restrict__ bb1, const float* __restrict__ W2,
    const float* __restrict__ bb2, const float* __restrict__ mlpW,
    const float* __restrict__ mlpb,
    float* __restrict__ out, int B)
{
    __shared__ float kv[WAVES_PB * T_TOK * KVSTRIDE];   // 16000 B

    const int lane = threadIdx.x & 63;
    const int wid  = threadIdx.x >> 6;
    const int gimg = blockIdx.x * WAVES_PB + wid;   // wave-uniform
    if (gimg >= B) return;
    const int t = (lane < T_TOK) ? lane : (T_TOK - 1);
    float* __restrict__ kvw = kv + wid * (T_TOK * KVSTRIDE);

    // ---- patch embed + positional ----
    fx2 x2[4];
    {
        const float FR[4] = {1.f, 0.1f, 0.01f, 0.001f};
        float pos[8];
        #pragma unroll
        for (int j = 0; j < 8; ++j) {
            float arg = (float)t * FR[j >> 1];
            pos[j] = (j & 1) ? __cosf(arg) : __sinf(arg);
        }
        float xs[8];
        if (t == 0) {
            #pragma unroll
            for (int e = 0; e < 8; ++e) xs[e] = cls[e] + pos[e];
        } else {
            const int p = t - 1, pr = p / 7, pc = p - pr * 7;
            const float* ib = images + (size_t)gimg * 784 + pr * 112 + pc * 4;
            float4 r0 = *reinterpret_cast<const float4*>(ib);
            float4 r1 = *reinterpret_cast<const float4*>(ib + 28);
            float4 r2 = *reinterpret_cast<const float4*>(ib + 56);
            float4 r3 = *reinterpret_cast<const float4*>(ib + 84);
            fx2 pf[8] = {{r0.x,r0.y},{r0.z,r0.w},{r1.x,r1.y},{r1.z,r1.w},
                         {r2.x,r2.y},{r2.z,r2.w},{r3.x,r3.y},{r3.z,r3.w}};
            #pragma unroll
            for (int e = 0; e < 8; ++e) {
                const fx2* lw = reinterpret_cast<const fx2*>(linW + e * 16);
                fx2 a = pf[0] * lw[0];
                #pragma unroll
                for (int i = 1; i < 8; ++i) a += pf[i] * lw[i];
                xs[e] = hadd(a) + pos[e];
            }
        }
        #pragma unroll
        for (int i = 0; i < 4; ++i) x2[i] = (fx2){xs[2*i], xs[2*i+1]};
    }

    #pragma unroll 1
    for (int blk = 0; blk < 4; ++blk) {
        const int w8 = blk * 8, w64 = blk * 64, w256 = blk * 256, w32 = blk * 32;

        // ---- LN1 ----
        fx2 h[4];
        {
            fx2 sm = x2[0] + x2[1] + x2[2] + x2[3];
            float mu = hadd(sm) * 0.125f;
            fx2 mu2 = {mu, mu};
            fx2 d0 = x2[0]-mu2, d1 = x2[1]-mu2, d2 = x2[2]-mu2, d3 = x2[3]-mu2;
            fx2 vr = d0*d0 + d1*d1 + d2*d2 + d3*d3;
            float rs = rsqrtf(hadd(vr) * 0.125f + 1e-5f);
            fx2 rsv = {rs, rs};
            const fx2* gg = reinterpret_cast<const fx2*>(g1 + w8);
            const fx2* bb = reinterpret_cast<const fx2*>(be1 + w8);
            h[0] = d0*rsv*gg[0] + bb[0]; h[1] = d1*rsv*gg[1] + bb[1];
            h[2] = d2*rsv*gg[2] + bb[2]; h[3] = d3*rsv*gg[3] + bb[3];
        }

        // ---- q,k,v ----
        float qs[8], ks[8], vs[8];
        #pragma unroll
        for (int e = 0; e < 8; ++e) {
            const fx2* wq = reinterpret_cast<const fx2*>(Wq + w64 + e*8);
            const fx2* wk = reinterpret_cast<const fx2*>(Wk + w64 + e*8);
            const fx2* wv = reinterpret_cast<const fx2*>(Wv + w64 + e*8);
            fx2 aq = h[0]*wq[0] + h[1]*wq[1] + h[2]*wq[2] + h[3]*wq[3];
            fx2 ak = h[0]*wk[0] + h[1]*wk[1] + h[2]*wk[2] + h[3]*wk[3];
            fx2 av = h[0]*wv[0] + h[1]*wv[1] + h[2]*wv[2] + h[3]*wv[3];
            qs[e] = hadd(aq) * QSCALE;
            ks[e] = hadd(ak);
            vs[e] = hadd(av);
        }
        {
            float* kvp = kvw + t * KVSTRIDE;
            *reinterpret_cast<float4*>(kvp +  0) = make_float4(ks[0],ks[1],ks[2],ks[3]);
            *reinterpret_cast<float4*>(kvp +  4) = make_float4(ks[4],ks[5],ks[6],ks[7]);
            *reinterpret_cast<float4*>(kvp +  8) = make_float4(vs[0],vs[1],vs[2],vs[3]);
            *reinterpret_cast<float4*>(kvp + 12) = make_float4(vs[4],vs[5],vs[6],vs[7]);
        }

        // ---- attention: broadcast LDS reads (uniform s), packed math ----
        const fx2 q01 = {qs[0],qs[1]}, q23 = {qs[2],qs[3]};
        const fx2 q45 = {qs[4],qs[5]}, q67 = {qs[6],qs[7]};
        float l0 = 0.f, l1 = 0.f;
        fx2 ac0 = {0,0}, ac1 = {0,0}, ac2 = {0,0}, ac3 = {0,0};
        #pragma unroll 2
        for (int s = 0; s < T_TOK; ++s) {
            const float* sp = kvw + s * KVSTRIDE;
            fx2 k0 = *reinterpret_cast<const fx2*>(sp + 0);
            fx2 k1 = *reinterpret_cast<const fx2*>(sp + 2);
            fx2 k2 = *reinterpret_cast<const fx2*>(sp + 4);
            fx2 k3 = *reinterpret_cast<const fx2*>(sp + 6);
            float p0 = FASTEXP(hadd(q01*k0 + q23*k1));
            float p1 = FASTEXP(hadd(q45*k2 + q67*k3));
            fx2 v0 = *reinterpret_cast<const fx2*>(sp + 8);
            fx2 v1 = *reinterpret_cast<const fx2*>(sp + 10);
            fx2 v2 = *reinterpret_cast<const fx2*>(sp + 12);
            fx2 v3 = *reinterpret_cast<const fx2*>(sp + 14);
            l0 += p0; l1 += p1;
            fx2 p02 = {p0,p0}, p12 = {p1,p1};
            ac0 += p02*v0; ac1 += p02*v1; ac2 += p12*v2; ac3 += p12*v3;
        }
        fx2 o[4];
        {
            float r0 = 1.f / l0, r1 = 1.f / l1;
            fx2 r02 = {r0,r0}, r12 = {r1,r1};
            o[0] = ac0*r02; o[1] = ac1*r02; o[2] = ac2*r12; o[3] = ac3*r12;
        }

        // ---- proj + residual ----
        fx2 xn[4];
        {
            float pr_[8];
            #pragma unroll
            for (int e = 0; e < 8; ++e) {
                const fx2* pw = reinterpret_cast<const fx2*>(Pw + w64 + e*8);
                fx2 a = o[0]*pw[0] + o[1]*pw[1] + o[2]*pw[2] + o[3]*pw[3];
                pr_[e] = hadd(a) + Pb[w8 + e];
            }
            #pragma unroll
            for (int i = 0; i < 4; ++i)
                xn[i] = x2[i] + (fx2){pr_[2*i], pr_[2*i+1]};
        }

        // ---- LN2 ----
        fx2 h2[4];
        {
            fx2 sm = xn[0] + xn[1] + xn[2] + xn[3];
            float mu = hadd(sm) * 0.125f;
            fx2 mu2 = {mu, mu};
            fx2 d0 = xn[0]-mu2, d1 = xn[1]-mu2, d2 = xn[2]-mu2, d3 = xn[3]-mu2;
            fx2 vr = d0*d0 + d1*d1 + d2*d2 + d3*d3;
            float rs = rsqrtf(hadd(vr) * 0.125f + 1e-5f);
            fx2 rsv = {rs, rs};
            const fx2* gg = reinterpret_cast<const fx2*>(g2 + w8);
            const fx2* bb = reinterpret_cast<const fx2*>(be2 + w8);
            h2[0] = d0*rsv*gg[0] + bb[0]; h2[1] = d1*rsv*gg[1] + bb[1];
            h2[2] = d2*rsv*gg[2] + bb[2]; h2[3] = d3*rsv*gg[3] + bb[3];
        }

        // ---- FF (f in pairs; acc2[d] holds pair-partials of acc[d]) ----
        {
            fx2 acc2[8];
            #pragma unroll
            for (int d = 0; d < 8; ++d) acc2[d] = (fx2){0.f, 0.f};
            #pragma unroll 4
            for (int fp = 0; fp < 16; ++fp) {
                const int f = fp * 2;
                const fx2* w1a = reinterpret_cast<const fx2*>(W1 + w256 + f*8);
                const fx2* w1b = w1a + 4;
                fx2 a0v = h2[0]*w1a[0] + h2[1]*w1a[1] + h2[2]*w1a[2] + h2[3]*w1a[3];
                fx2 a1v = h2[0]*w1b[0] + h2[1]*w1b[1] + h2[2]*w1b[2] + h2[3]*w1b[3];
                float a0 = fmaxf(hadd(a0v) + bb1[w32 + f],     0.f);
                float a1 = fmaxf(hadd(a1v) + bb1[w32 + f + 1], 0.f);
                fx2 af = {a0, a1};
                #pragma unroll
                for (int d = 0; d < 8; ++d)
                    acc2[d] += af * *reinterpret_cast<const fx2*>(W2 + w256 + d*32 + f);
            }
            const fx2* bb = reinterpret_cast<const fx2*>(bb2 + w8);
            #pragma unroll
            for (int i = 0; i < 4; ++i)
                x2[i] = xn[i] + (fx2){hadd(acc2[2*i]), hadd(acc2[2*i+1])} + bb[i];
        }
    }

    // ---- classification head: lane 0 (token 0) ----
    if (lane == 0) {
        float lg[10]; float mx = -1e30f;
        #pragma unroll
        for (int c = 0; c < 10; ++c) {
            const fx2* mw = reinterpret_cast<const fx2*>(mlpW + c*8);
            fx2 a = x2[0]*mw[0] + x2[1]*mw[1] + x2[2]*mw[2] + x2[3]*mw[3];
            lg[c] = hadd(a) + mlpb[c];
            mx = fmaxf(mx, lg[c]);
        }
        float ssum = 0.f;
        #pragma unroll
        for (int c = 0; c < 10; ++c) { lg[c] = __expf(lg[c] - mx); ssum += lg[c]; }
        const float rsum = 1.f / ssum;
        #pragma unroll
        for (int c = 0; c < 10; ++c)
            out[(size_t)gimg*10 + c] = lg[c] * rsum;
    }
}

extern "C" void kernel_launch(void* const* d_in, const int* in_sizes, int n_in,
                              void* d_out, int out_size, void* d_ws, size_t ws_size,
                              hipStream_t stream) {
    const int B = in_sizes[0] / 784;
    const int nblk = (B + WAVES_PB - 1) / WAVES_PB;
    vit_fwd<<<nblk, THREADS, 0, stream>>>(
        (const float*)d_in[0],  (const float*)d_in[1],  (const float*)d_in[2],
        (const float*)d_in[3],  (const float*)d_in[4],  (const float*)d_in[5],
        (const float*)d_in[6],  (const float*)d_in[7],  (const float*)d_in[8],
        (const float*)d_in[9],  (const float*)d_in[10], (const float*)d_in[11],
        (const float*)d_in[12], (const float*)d_in[13], (const float*)d_in[14],
        (const float*)d_in[15], (const float*)d_in[16], (const float*)d_in[17],
        (float*)d_out, B);
}

// Round 6
// 97.716 us; speedup vs baseline: 2.1921x; 1.0719x over previous
//
#include <hip/hip_runtime.h>

// Tiny ViT forward, B=8192, fp32. Wave-per-IMAGE-PAIR: lane t owns token t
// of images (2w, 2w+1); the two fx2 halves are the two images. Every
// d-reduction is then a chain of v_pk_fma_f32 with SGPR-broadcast weights
// (no hadd extracts), and the pair halves are independent dots. K/V live
// in a per-wave LDS region as image-pairs (one broadcast read serves both
// images); no __syncthreads anywhere (single-wave producer/consumer).
// Weights via wave-uniform global loads (s_load). One-pass softmax
// without max subtraction (scores ~0.06 std; exp-safe).

typedef float fx2 __attribute__((ext_vector_type(2)));

#define T_TOK    50
#define WAVES_PB 4
#define THREADS  (WAVES_PB * 64)
#define KVSTRIDE 36                  // floats per token: 32 + 4 pad
#define SCALE    0.35355339059327373f   // 8^-0.5

#if __has_builtin(__builtin_amdgcn_exp2f)
  #define FASTEXP(x) __builtin_amdgcn_exp2f(x)
  #define QSCALE (SCALE * 1.4426950408889634f)   // fold log2(e) into q
#else
  #define FASTEXP(x) __expf(x)
  #define QSCALE SCALE
#endif

__device__ __forceinline__ fx2 bc(float s)    { return (fx2){s, s}; }
__device__ __forceinline__ fx2 lo4(float4 u)  { return (fx2){u.x, u.y}; }
__device__ __forceinline__ fx2 hi4(float4 u)  { return (fx2){u.z, u.w}; }
__device__ __forceinline__ fx2 fmax2(fx2 a, fx2 b) {
    return (fx2){fmaxf(a.x, b.x), fmaxf(a.y, b.y)};
}
__device__ __forceinline__ fx2 expboth(fx2 v) {
    return (fx2){FASTEXP(v.x), FASTEXP(v.y)};
}

__global__ __launch_bounds__(THREADS) void vit_fwd(
    const float* __restrict__ images, const float* __restrict__ cls,
    const float* __restrict__ linW,
    const float* __restrict__ g1,  const float* __restrict__ be1,
    const float* __restrict__ Wq,  const float* __restrict__ Wk,
    const float* __restrict__ Wv,  const float* __restrict__ Pw,
    const float* __restrict__ Pb,  const float* __restrict__ g2,
    const float* __restrict__ be2, const float* __restrict__ W1,
    const float* __restrict__ bb1, const float* __restrict__ W2,
    const float* __restrict__ bb2, const float* __restrict__ mlpW,
    const float* __restrict__ mlpb,
    float* __restrict__ out, int B)
{
    __shared__ float kv[WAVES_PB * T_TOK * KVSTRIDE];   // 28800 B

    const int lane = threadIdx.x & 63;
    const int wid  = threadIdx.x >> 6;
    const int pair = blockIdx.x * WAVES_PB + wid;   // wave-uniform
    const int gA   = pair * 2;
    if (gA >= B) return;
    const bool hasB = (gA + 1) < B;
    const int gB   = hasB ? gA + 1 : gA;
    const int t    = (lane < T_TOK) ? lane : (T_TOK - 1);
    float* __restrict__ kvw = kv + wid * (T_TOK * KVSTRIDE);

    // ---- patch embed + positional (pos depends only on t: shared) ----
    fx2 x[8];
    {
        const float FR[4] = {1.f, 0.1f, 0.01f, 0.001f};
        float pos[8];
        #pragma unroll
        for (int j = 0; j < 8; ++j) {
            float arg = (float)t * FR[j >> 1];
            pos[j] = (j & 1) ? __cosf(arg) : __sinf(arg);
        }
        if (t == 0) {
            #pragma unroll
            for (int e = 0; e < 8; ++e) x[e] = bc(cls[e] + pos[e]);
        } else {
            const int p = t - 1, pr = p / 7, pc = p - pr * 7;
            const size_t off = (size_t)pr * 112 + pc * 4;
            const float* ibA = images + (size_t)gA * 784 + off;
            const float* ibB = images + (size_t)gB * 784 + off;
            fx2 pf[16];
            #pragma unroll
            for (int r = 0; r < 4; ++r) {
                float4 ua = *reinterpret_cast<const float4*>(ibA + r * 28);
                float4 ub = *reinterpret_cast<const float4*>(ibB + r * 28);
                pf[r*4+0] = (fx2){ua.x, ub.x}; pf[r*4+1] = (fx2){ua.y, ub.y};
                pf[r*4+2] = (fx2){ua.z, ub.z}; pf[r*4+3] = (fx2){ua.w, ub.w};
            }
            #pragma unroll
            for (int e = 0; e < 8; ++e) {
                fx2 a = bc(pos[e]);
                #pragma unroll
                for (int i = 0; i < 16; ++i) a += pf[i] * bc(linW[e*16 + i]);
                x[e] = a;
            }
        }
    }

    #pragma unroll 1
    for (int blk = 0; blk < 4; ++blk) {
        const int w8 = blk * 8, w64 = blk * 64, w256 = blk * 256, w32 = blk * 32;

        // ---- LN1 (both images in parallel) ----
        fx2 h[8];
        {
            fx2 mu = x[0];
            #pragma unroll
            for (int d = 1; d < 8; ++d) mu += x[d];
            mu *= bc(0.125f);
            fx2 var = bc(0.f);
            #pragma unroll
            for (int d = 0; d < 8; ++d) { fx2 dd = x[d] - mu; var += dd * dd; }
            var = var * bc(0.125f) + bc(1e-5f);
            fx2 rs = {rsqrtf(var.x), rsqrtf(var.y)};
            #pragma unroll
            for (int d = 0; d < 8; ++d)
                h[d] = (x[d] - mu) * rs * bc(g1[w8 + d]) + bc(be1[w8 + d]);
        }

        // ---- q,k,v: pure pk_fma chains with SGPR weights ----
        fx2 q[8], kk[8], vv[8];
        #pragma unroll
        for (int e = 0; e < 8; ++e) {
            fx2 aq = bc(0.f), ak = bc(0.f), av = bc(0.f);
            #pragma unroll
            for (int d = 0; d < 8; ++d) {
                aq += h[d] * bc(Wq[w64 + e*8 + d]);
                ak += h[d] * bc(Wk[w64 + e*8 + d]);
                av += h[d] * bc(Wv[w64 + e*8 + d]);
            }
            q[e] = aq * bc(QSCALE); kk[e] = ak; vv[e] = av;
        }
        {   // K pairs then V pairs, interleaved [kA0,kB0,kA1,kB1,...]
            float* kvp = kvw + t * KVSTRIDE;
            *reinterpret_cast<float4*>(kvp +  0) = make_float4(kk[0].x,kk[0].y,kk[1].x,kk[1].y);
            *reinterpret_cast<float4*>(kvp +  4) = make_float4(kk[2].x,kk[2].y,kk[3].x,kk[3].y);
            *reinterpret_cast<float4*>(kvp +  8) = make_float4(kk[4].x,kk[4].y,kk[5].x,kk[5].y);
            *reinterpret_cast<float4*>(kvp + 12) = make_float4(kk[6].x,kk[6].y,kk[7].x,kk[7].y);
            *reinterpret_cast<float4*>(kvp + 16) = make_float4(vv[0].x,vv[0].y,vv[1].x,vv[1].y);
            *reinterpret_cast<float4*>(kvp + 20) = make_float4(vv[2].x,vv[2].y,vv[3].x,vv[3].y);
            *reinterpret_cast<float4*>(kvp + 24) = make_float4(vv[4].x,vv[4].y,vv[5].x,vv[5].y);
            *reinterpret_cast<float4*>(kvp + 28) = make_float4(vv[6].x,vv[6].y,vv[7].x,vv[7].y);
        }

        // ---- attention: broadcast LDS reads (uniform s), all packed ----
        fx2 l0 = bc(0.f), l1 = bc(0.f);
        fx2 acc[8];
        #pragma unroll
        for (int d = 0; d < 8; ++d) acc[d] = bc(0.f);
        #pragma unroll 2
        for (int s = 0; s < T_TOK; ++s) {
            const float* sp = kvw + s * KVSTRIDE;
            float4 k01 = *reinterpret_cast<const float4*>(sp +  0);
            float4 k23 = *reinterpret_cast<const float4*>(sp +  4);
            float4 k45 = *reinterpret_cast<const float4*>(sp +  8);
            float4 k67 = *reinterpret_cast<const float4*>(sp + 12);
            fx2 d0 = q[0]*lo4(k01) + q[1]*hi4(k01) + q[2]*lo4(k23) + q[3]*hi4(k23);
            fx2 d1 = q[4]*lo4(k45) + q[5]*hi4(k45) + q[6]*lo4(k67) + q[7]*hi4(k67);
            fx2 p0 = expboth(d0), p1 = expboth(d1);
            l0 += p0; l1 += p1;
            float4 v01 = *reinterpret_cast<const float4*>(sp + 16);
            float4 v23 = *reinterpret_cast<const float4*>(sp + 20);
            float4 v45 = *reinterpret_cast<const float4*>(sp + 24);
            float4 v67 = *reinterpret_cast<const float4*>(sp + 28);
            acc[0] += p0*lo4(v01); acc[1] += p0*hi4(v01);
            acc[2] += p0*lo4(v23); acc[3] += p0*hi4(v23);
            acc[4] += p1*lo4(v45); acc[5] += p1*hi4(v45);
            acc[6] += p1*lo4(v67); acc[7] += p1*hi4(v67);
        }
        fx2 o[8];
        {
            fx2 r0 = {1.f / l0.x, 1.f / l0.y};
            fx2 r1 = {1.f / l1.x, 1.f / l1.y};
            #pragma unroll
            for (int d = 0; d < 4; ++d) { o[d] = acc[d] * r0; o[d+4] = acc[d+4] * r1; }
        }

        // ---- proj + residual ----
        fx2 xn[8];
        #pragma unroll
        for (int e = 0; e < 8; ++e) {
            fx2 a = bc(Pb[w8 + e]);
            #pragma unroll
            for (int d = 0; d < 8; ++d) a += o[d] * bc(Pw[w64 + e*8 + d]);
            xn[e] = x[e] + a;
        }

        // ---- LN2 ----
        fx2 h2[8];
        {
            fx2 mu = xn[0];
            #pragma unroll
            for (int d = 1; d < 8; ++d) mu += xn[d];
            mu *= bc(0.125f);
            fx2 var = bc(0.f);
            #pragma unroll
            for (int d = 0; d < 8; ++d) { fx2 dd = xn[d] - mu; var += dd * dd; }
            var = var * bc(0.125f) + bc(1e-5f);
            fx2 rs = {rsqrtf(var.x), rsqrtf(var.y)};
            #pragma unroll
            for (int d = 0; d < 8; ++d)
                h2[d] = (xn[d] - mu) * rs * bc(g2[w8 + d]) + bc(be2[w8 + d]);
        }

        // ---- FF ----
        {
            fx2 acc2[8];
            #pragma unroll
            for (int d = 0; d < 8; ++d) acc2[d] = bc(0.f);
            #pragma unroll 4
            for (int f = 0; f < 32; ++f) {
                fx2 a = bc(bb1[w32 + f]);
                #pragma unroll
                for (int d = 0; d < 8; ++d) a += h2[d] * bc(W1[w256 + f*8 + d]);
                a = fmax2(a, bc(0.f));
                #pragma unroll
                for (int d = 0; d < 8; ++d) acc2[d] += a * bc(W2[w256 + d*32 + f]);
            }
            #pragma unroll
            for (int d = 0; d < 8; ++d) x[d] = xn[d] + acc2[d] + bc(bb2[w8 + d]);
        }
    }

    // ---- classification head: lane 0 (token 0), both images ----
    if (lane == 0) {
        fx2 lg[10]; fx2 mx = bc(-1e30f);
        #pragma unroll
        for (int c = 0; c < 10; ++c) {
            fx2 a = bc(mlpb[c]);
            #pragma unroll
            for (int d = 0; d < 8; ++d) a += x[d] * bc(mlpW[c*8 + d]);
            lg[c] = a; mx = fmax2(mx, a);
        }
        fx2 ssum = bc(0.f);
        #pragma unroll
        for (int c = 0; c < 10; ++c) {
            fx2 e = lg[c] - mx;
            lg[c] = (fx2){__expf(e.x), __expf(e.y)};
            ssum += lg[c];
        }
        const float rA = 1.f / ssum.x, rB = 1.f / ssum.y;
        #pragma unroll
        for (int c = 0; c < 10; ++c) {
            out[(size_t)gA*10 + c] = lg[c].x * rA;
            if (hasB) out[(size_t)gB*10 + c] = lg[c].y * rB;
        }
    }
}

extern "C" void kernel_launch(void* const* d_in, const int* in_sizes, int n_in,
                              void* d_out, int out_size, void* d_ws, size_t ws_size,
                              hipStream_t stream) {
    const int B = in_sizes[0] / 784;
    const int pairs = (B + 1) / 2;
    const int nblk = (pairs + WAVES_PB - 1) / WAVES_PB;
    vit_fwd<<<nblk, THREADS, 0, stream>>>(
        (const float*)d_in[0],  (const float*)d_in[1],  (const float*)d_in[2],
        (const float*)d_in[3],  (const float*)d_in[4],  (const float*)d_in[5],
        (const float*)d_in[6],  (const float*)d_in[7],  (const float*)d_in[8],
        (const float*)d_in[9],  (const float*)d_in[10], (const float*)d_in[11],
        (const float*)d_in[12], (const float*)d_in[13], (const float*)d_in[14],
        (const float*)d_in[15], (const float*)d_in[16], (const float*)d_in[17],
        (float*)d_out, B);
}